// Round 4
// baseline (550.923 us; speedup 1.0000x reference)
//
#include <hip/hip_runtime.h>

#define Q 2048
#define NTRAIN 65536
#define D 768
#define KNN 7

#define BM 256
#define BN 256
#define BK 64
#define KT (D / BK)          // 12
#define NCT (NTRAIN / BN)    // 256 column tiles
#define TSEL 8               // candidates kept per (row, tile)

typedef __attribute__((ext_vector_type(8))) short short8;
typedef __attribute__((ext_vector_type(4))) float f32x4;

// ---- ws layout (bytes) ----
static constexpr size_t XB_OFF   = 0;
static constexpr size_t TB_OFF   = XB_OFF + (size_t)Q * D * 2;
static constexpr size_t TSQ_OFF  = TB_OFF + (size_t)NTRAIN * D * 2;
static constexpr size_t CAND_OFF = TSQ_OFF + (size_t)NTRAIN * 4;

__device__ __forceinline__ unsigned short f2b(float f) {
    unsigned u = __float_as_uint(f);
    unsigned r = (u + 0x7FFFu + ((u >> 16) & 1u)) >> 16;   // RNE bf16
    return (unsigned short)r;
}

__device__ __forceinline__ unsigned pack32(float f) {
    unsigned u = __float_as_uint(f);
    return u ^ (unsigned)(((int)u >> 31) | 0x80000000);    // monotone map
}

__device__ __forceinline__ void gload16(const void* g, void* l) {
    __builtin_amdgcn_global_load_lds(
        (const __attribute__((address_space(1))) unsigned*)g,
        (__attribute__((address_space(3))) unsigned*)l, 16, 0, 0);
}

// ---------------- Kernel 1: fused fp32 -> bf16 + row sq-norms ----------------
__global__ void prep_kernel(const float* __restrict__ X,
                            const float* __restrict__ Xt,
                            unsigned short* __restrict__ Xb,
                            unsigned short* __restrict__ Tb,
                            float* __restrict__ tsq) {
    __shared__ float red[3];
    const int b = blockIdx.x;
    const int t = threadIdx.x;
    const bool isX = (b < Q);
    const int row = isX ? b : b - Q;
    const float* src = isX ? X : Xt;
    unsigned short* dst = isX ? Xb : Tb;
    float4 v = reinterpret_cast<const float4*>(src)[(size_t)row * (D / 4) + t];
    ushort4 o;
    o.x = f2b(v.x); o.y = f2b(v.y); o.z = f2b(v.z); o.w = f2b(v.w);
    reinterpret_cast<ushort4*>(dst)[(size_t)row * (D / 4) + t] = o;
    if (!isX) {
        float s = v.x * v.x + v.y * v.y + v.z * v.z + v.w * v.w;
#pragma unroll
        for (int off = 32; off; off >>= 1) s += __shfl_down(s, off);
        if ((t & 63) == 0) red[t >> 6] = s;
        __syncthreads();
        if (t == 0) tsq[row] = red[0] + red[1] + red[2];
    }
}

// ---------------- Kernel 2: 256^2 counted-vmcnt MFMA GEMM + per-tile top-8 ----------------
__global__ void __launch_bounds__(512, 2) knn_gemm_kernel(
    const unsigned short* __restrict__ Xb, const unsigned short* __restrict__ Tb,
    const float* __restrict__ tsq, unsigned* __restrict__ cand) {
    // K-loop: A0[256][64] | A1 | B0 | B1 (bf16, XOR-swizzled granules)
    // epilogue: keys u16[256][256] (col-swizzled) reuses all 128 KiB
    __shared__ __align__(16) char smem[131072];
    const int tid  = threadIdx.x;
    const int wave = tid >> 6, lane = tid & 63;
    const int colTile = blockIdx.x, rowTile = blockIdx.y;   // colTile fastest -> same-colTile blocks share XCD
    const int wr = wave >> 2, wc = wave & 3;                // 2 x 4 wave grid; per-wave out 128x64

    const f32x4 zero = {0.f, 0.f, 0.f, 0.f};
    f32x4 acc[8][4];
#pragma unroll
    for (int m = 0; m < 8; m++)
#pragma unroll
        for (int n = 0; n < 4; n++) acc[m][n] = zero;

    // ---- kt-invariant swizzled frag byte-offsets (k-slice 0; slice 1 = ^64) ----
    int aOff[8], bOff[4];
    const int g0 = lane >> 4;
#pragma unroll
    for (int m = 0; m < 8; m++) {
        const int rowA = wr * 128 + m * 16 + (lane & 15);
        aOff[m] = rowA * 128 + ((g0 ^ (rowA & 7)) << 4);
    }
#pragma unroll
    for (int n = 0; n < 4; n++) {
        const int rowB = wc * 64 + n * 16 + (lane & 15);
        bOff[n] = rowB * 128 + ((g0 ^ (rowB & 7)) << 4);
    }

    // ---- staging: chunk c covers rows [c*64, c*64+64); lds byte = c*8192 + wave*1024 + lane*16 ----
    const int s_row = wave * 8 + (lane >> 3);                  // 0..63
    const int s_col = (((lane & 7) ^ (lane >> 3)) << 3);       // pre-swizzled source granule
    const unsigned short* pA = Xb + (size_t)(rowTile * BM + s_row) * D + s_col;
    const unsigned short* pB = Tb + (size_t)(colTile * BN + s_row) * D + s_col;
    char* const A0 = smem;
    char* const A1 = smem + 32768;
    char* const B0 = smem + 65536;
    char* const B1 = smem + 98304;
    const int ldsS = wave * 1024;

    auto stage = [&](int elemOff, char* AD, char* BD) __attribute__((always_inline)) {
#pragma unroll
        for (int c = 0; c < 4; ++c) {
            gload16(pA + (size_t)c * (64 * D) + elemOff, AD + c * 8192 + ldsS);
            gload16(pB + (size_t)c * (64 * D) + elemOff, BD + c * 8192 + ldsS);
        }
    };

    // prologue: stage tiles 0,1; counted wait for tile 0 only
    stage(0, A0, B0);
    stage(BK, A1, B1);
    asm volatile("s_waitcnt vmcnt(8)" ::: "memory");
    __builtin_amdgcn_sched_barrier(0);
    __builtin_amdgcn_s_barrier();

    auto kbody = [&](int t, char* CA, char* CB) __attribute__((always_inline)) {
        short8 a0[8], b0[4], a1[8], b1[4];
#pragma unroll
        for (int m = 0; m < 8; ++m) a0[m] = *(const short8*)(CA + aOff[m]);
#pragma unroll
        for (int n = 0; n < 4; ++n) b0[n] = *(const short8*)(CB + bOff[n]);
#pragma unroll
        for (int m = 0; m < 8; ++m) a1[m] = *(const short8*)(CA + (aOff[m] ^ 64));
#pragma unroll
        for (int n = 0; n < 4; ++n) b1[n] = *(const short8*)(CB + (bOff[n] ^ 64));
        // k-slice 0 MFMAs (compiler inserts counted lgkm waits for a0/b0)
        __builtin_amdgcn_s_setprio(1);
#pragma unroll
        for (int m = 0; m < 8; ++m)
#pragma unroll
            for (int n = 0; n < 4; ++n)
                acc[m][n] = __builtin_amdgcn_mfma_f32_16x16x32_bf16(a0[m], b0[n], acc[m][n], 0, 0, 0);
        __builtin_amdgcn_s_setprio(0);
        // all my reads of this buffer done -> all waves done -> safe to overwrite
        asm volatile("s_waitcnt lgkmcnt(0)" ::: "memory");
        __builtin_amdgcn_sched_barrier(0);
        __builtin_amdgcn_s_barrier();
        if (t < KT - 2) stage(2 * BK, CA, CB);   // tile t+2 into just-freed buffer
        // k-slice 1 MFMAs overlap the staging loads
        __builtin_amdgcn_s_setprio(1);
#pragma unroll
        for (int m = 0; m < 8; ++m)
#pragma unroll
            for (int n = 0; n < 4; ++n)
                acc[m][n] = __builtin_amdgcn_mfma_f32_16x16x32_bf16(a1[m], b1[n], acc[m][n], 0, 0, 0);
        __builtin_amdgcn_s_setprio(0);
        // counted wait: tile t+1's 8 loads done; tile t+2's 8 stay in flight
        if (t < KT - 2) { asm volatile("s_waitcnt vmcnt(8)" ::: "memory"); }
        else            { asm volatile("s_waitcnt vmcnt(0)" ::: "memory"); }
        __builtin_amdgcn_sched_barrier(0);
        __builtin_amdgcn_s_barrier();
        pA += BK; pB += BK;
    };

    for (int it = 0; it < KT; it += 2) {
        kbody(it,     A0, B0);
        kbody(it + 1, A1, B1);
    }

    // ---- epilogue: keys + per-tile top-8 ----
    float tsqv[4];
#pragma unroll
    for (int n = 0; n < 4; n++)
        tsqv[n] = tsq[colTile * BN + wc * 64 + n * 16 + (lane & 15)];

    unsigned short* keys = (unsigned short*)smem;   // [256][256] swizzled
    const int crow = wr * 128 + ((lane >> 4) << 2);
    const int ccol = wc * 64 + (lane & 15);
#pragma unroll
    for (int m = 0; m < 8; m++)
#pragma unroll
        for (int n = 0; n < 4; n++)
#pragma unroll
            for (int r = 0; r < 4; r++) {
                const int row = crow + m * 16 + r;
                const int col = ccol + n * 16;
                float key = fmaf(-2.f, acc[m][n][r], tsqv[n]);
                keys[row * 256 + (col ^ ((row & 12) << 2))] =
                    (unsigned short)(pack32(key) >> 16);
            }
    __syncthreads();

    // branchless per-half top-4: 2 threads/row, each scans 64 u32 words (128 cols)
    const int srw = tid >> 1, h = tid & 1;
    const unsigned sx = (unsigned)((srw & 12) << 2);
    const unsigned* keys32 = (const unsigned*)smem;
    const unsigned base = (unsigned)(srw * 128 + h * 64);
    const unsigned gcb = (unsigned)(colTile * BN) + (unsigned)(h * 128);
    unsigned m1 = ~0u, m2 = ~0u, m3 = ~0u, m4 = ~0u;
#pragma unroll 8
    for (int ii = 0; ii < 64; ++ii) {
        const unsigned w = (unsigned)((ii + srw) & 63);
        const unsigned pair = keys32[base + w];
        const unsigned gc = gcb + ((w * 2) ^ sx);
        const unsigned v0 = (pair << 16) | gc;
        const unsigned v1 = (pair & 0xFFFF0000u) | (gc + 1);
        unsigned t0, t1, t2;
        t0 = max(m1, v0); m1 = min(m1, v0);
        t1 = max(m2, t0); m2 = min(m2, t0);
        t2 = max(m3, t1); m3 = min(m3, t1);
        m4 = min(m4, t2);
        t0 = max(m1, v1); m1 = min(m1, v1);
        t1 = max(m2, t0); m2 = min(m2, t0);
        t2 = max(m3, t1); m3 = min(m3, t1);
        m4 = min(m4, t2);
    }
    uint4 outv = {m1, m2, m3, m4};
    *reinterpret_cast<uint4*>(
        cand + ((size_t)(rowTile * BM + srw) * NCT + colTile) * TSEL + h * 4) = outv;
}

// ---------------- Kernel 3: approx top-16 -> exact fp32 re-rank -> mean ----------------
__global__ void __launch_bounds__(256) knn_reduce_kernel(
    const float* __restrict__ X, const float* __restrict__ Xt,
    const float* __restrict__ tsq, const float* __restrict__ y,
    const unsigned* __restrict__ cand, float* __restrict__ out) {
    __shared__ unsigned cl[2048];
    __shared__ float xrow[D];
    __shared__ float red[4];
    __shared__ unsigned wmin[4];
    __shared__ float xsqs;
    __shared__ unsigned sel[16];
    __shared__ float exd[16];
    __shared__ unsigned exi[16];
    const int q = blockIdx.x;
    const int tid = threadIdx.x;
    const int lane = tid & 63, wave = tid >> 6;

    const unsigned* cq = cand + (size_t)q * (NCT * TSEL);
#pragma unroll
    for (int j = 0; j < 8; j++) cl[j * 256 + tid] = cq[j * 256 + tid];
    if (tid < D / 4)
        ((float4*)xrow)[tid] = ((const float4*)(X + (size_t)q * D))[tid];
    __syncthreads();

    float xs = 0.f;
#pragma unroll
    for (int j = 0; j < 3; j++) { float v = xrow[tid + j * 256]; xs = fmaf(v, v, xs); }
#pragma unroll
    for (int off = 32; off; off >>= 1) xs += __shfl_down(xs, off);
    if (lane == 0) red[wave] = xs;
    __syncthreads();
    if (tid == 0) xsqs = red[0] + red[1] + red[2] + red[3];

    for (int r = 0; r < 16; r++) {
        unsigned mn = 0xFFFFFFFFu;
#pragma unroll
        for (int j = 0; j < 8; j++) { unsigned v = cl[tid + 256 * j]; mn = v < mn ? v : mn; }
#pragma unroll
        for (int off = 32; off; off >>= 1) {
            unsigned o = (unsigned)__shfl_xor((int)mn, off);
            mn = o < mn ? o : mn;
        }
        if (lane == 0) wmin[wave] = mn;
        __syncthreads();
        unsigned m01 = wmin[0] < wmin[1] ? wmin[0] : wmin[1];
        unsigned m23 = wmin[2] < wmin[3] ? wmin[2] : wmin[3];
        unsigned m = m01 < m23 ? m01 : m23;
        if (tid == 0) sel[r] = m;
#pragma unroll
        for (int j = 0; j < 8; j++)
            if (cl[tid + 256 * j] == m) cl[tid + 256 * j] = 0xFFFFFFFFu;
        __syncthreads();
    }

    for (int cc = wave; cc < 16; cc += 4) {
        const unsigned id = sel[cc] & 0xFFFFu;
        const float* trow = Xt + (size_t)id * D;
        float s = 0.f;
#pragma unroll
        for (int j = 0; j < 12; j++) s = fmaf(xrow[lane + j * 64], trow[lane + j * 64], s);
#pragma unroll
        for (int off = 32; off; off >>= 1) s += __shfl_xor(s, off);
        if (lane == 0) {
            float d2 = xsqs + tsq[id] - 2.f * s;
            exd[cc] = sqrtf(fmaxf(d2, 0.f));
            exi[cc] = id;
        }
    }
    __syncthreads();

    if (tid == 0) {
        bool taken[16];
#pragma unroll
        for (int j = 0; j < 16; j++) taken[j] = false;
        float accy = 0.f;
        for (int k = 0; k < KNN; k++) {
            int best = -1;
            for (int j = 0; j < 16; j++) {
                if (taken[j]) continue;
                if (best < 0 || exd[j] < exd[best] ||
                    (exd[j] == exd[best] && exi[j] < exi[best])) best = j;
            }
            taken[best] = true;
            accy += y[exi[best]];
        }
        out[q] = accy / 7.0f;
    }
}

extern "C" void kernel_launch(void* const* d_in, const int* in_sizes, int n_in,
                              void* d_out, int out_size, void* d_ws, size_t ws_size,
                              hipStream_t stream) {
    const float* X  = (const float*)d_in[0];
    const float* Xt = (const float*)d_in[1];
    const float* y  = (const float*)d_in[2];
    float* out = (float*)d_out;
    char* ws = (char*)d_ws;
    unsigned short* Xb = (unsigned short*)(ws + XB_OFF);
    unsigned short* Tb = (unsigned short*)(ws + TB_OFF);
    float* tsq = (float*)(ws + TSQ_OFF);
    unsigned* cand = (unsigned*)(ws + CAND_OFF);

    prep_kernel<<<dim3(Q + NTRAIN), dim3(192), 0, stream>>>(X, Xt, Xb, Tb, tsq);
    knn_gemm_kernel<<<dim3(NCT, Q / BM), dim3(512), 0, stream>>>(Xb, Tb, tsq, cand);
    knn_reduce_kernel<<<dim3(Q), dim3(256), 0, stream>>>(X, Xt, tsq, y, cand, out);
}

// Round 5
// 314.542 us; speedup vs baseline: 1.7515x; 1.7515x over previous
//
#include <hip/hip_runtime.h>

#define Q 2048
#define NTRAIN 65536
#define D 768
#define KNN 7

#define BM 128
#define BN 128
#define BK 64
#define KT (D / BK)          // 12
#define NCT (NTRAIN / BN)    // 512 column tiles
#define TSEL 8               // candidates kept per (row, tile)

typedef __attribute__((ext_vector_type(8))) short short8;
typedef __attribute__((ext_vector_type(4))) float f32x4;

// ---- ws layout (bytes) ----
static constexpr size_t XB_OFF   = 0;
static constexpr size_t TB_OFF   = XB_OFF + (size_t)Q * D * 2;
static constexpr size_t TSQ_OFF  = TB_OFF + (size_t)NTRAIN * D * 2;
static constexpr size_t CAND_OFF = TSQ_OFF + (size_t)NTRAIN * 4;

__device__ __forceinline__ unsigned short f2b(float f) {
    unsigned u = __float_as_uint(f);
    unsigned r = (u + 0x7FFFu + ((u >> 16) & 1u)) >> 16;   // RNE bf16
    return (unsigned short)r;
}

__device__ __forceinline__ unsigned pack32(float f) {
    unsigned u = __float_as_uint(f);
    return u ^ (unsigned)(((int)u >> 31) | 0x80000000);    // monotone map
}

__device__ __forceinline__ void gload16(const void* g, void* l) {
    __builtin_amdgcn_global_load_lds(
        (const __attribute__((address_space(1))) unsigned*)g,
        (__attribute__((address_space(3))) unsigned*)l, 16, 0, 0);
}

// ---------------- Kernel 1: fused fp32 -> bf16 + row sq-norms ----------------
__global__ void prep_kernel(const float* __restrict__ X,
                            const float* __restrict__ Xt,
                            unsigned short* __restrict__ Xb,
                            unsigned short* __restrict__ Tb,
                            float* __restrict__ tsq) {
    __shared__ float red[3];
    const int b = blockIdx.x;
    const int t = threadIdx.x;
    const bool isX = (b < Q);
    const int row = isX ? b : b - Q;
    const float* src = isX ? X : Xt;
    unsigned short* dst = isX ? Xb : Tb;
    float4 v = reinterpret_cast<const float4*>(src)[(size_t)row * (D / 4) + t];
    ushort4 o;
    o.x = f2b(v.x); o.y = f2b(v.y); o.z = f2b(v.z); o.w = f2b(v.w);
    reinterpret_cast<ushort4*>(dst)[(size_t)row * (D / 4) + t] = o;
    if (!isX) {
        float s = v.x * v.x + v.y * v.y + v.z * v.z + v.w * v.w;
#pragma unroll
        for (int off = 32; off; off >>= 1) s += __shfl_down(s, off);
        if ((t & 63) == 0) red[t >> 6] = s;
        __syncthreads();
        if (t == 0) tsq[row] = red[0] + red[1] + red[2];
    }
}

// ---------------- Kernel 2: bf16 MFMA GEMM + per-tile top-8 ----------------
__global__ void __launch_bounds__(256, 3) knn_gemm_kernel(
    const unsigned short* __restrict__ Xb, const unsigned short* __restrict__ Tb,
    const float* __restrict__ tsq, unsigned* __restrict__ cand) {
    // smem union: [0,16384) A-tile bf16[128][64], [16384,32768) B-tile
    // epilogue: [0,32768) keys u16[128][128] (col-swizzled)
    __shared__ __align__(16) char smem[32768];
    const int tid  = threadIdx.x;
    const int wave = tid >> 6, lane = tid & 63;

    // ---- T1 XCD-aware swizzle (bijective): XCD k owns colTiles [64k, 64k+64),
    // all 16 rowTiles of a colTile run on the same XCD back-to-back ----
    const int flat = blockIdx.y * 16 + blockIdx.x;       // dispatch order: flat%8 ~ XCD
    const int rowTile = (flat >> 3) & 15;
    const int colTile = (flat & 7) * 64 + (flat >> 7);

    const int wr = wave >> 1, wc = wave & 1;

    const f32x4 zero = {0.f, 0.f, 0.f, 0.f};
    f32x4 acc[4][4];
#pragma unroll
    for (int m = 0; m < 4; m++)
#pragma unroll
        for (int n = 0; n < 4; n++) acc[m][n] = zero;

    // ---- prefetch epilogue tsq values ----
    float tsqv[4];
#pragma unroll
    for (int n = 0; n < 4; n++)
        tsqv[n] = tsq[colTile * BN + wc * 64 + n * 16 + (lane & 15)];

    // ---- hoisted swizzled LDS frag byte-offsets (kt-invariant) ----
    int aOff[4][2], bOff[4][2];
#pragma unroll
    for (int m = 0; m < 4; m++) {
        const int rowA = wr * 64 + m * 16 + (lane & 15);
        const int rowB = wc * 64 + m * 16 + (lane & 15);
#pragma unroll
        for (int kk = 0; kk < 2; kk++) {
            const int g = kk * 4 + (lane >> 4);
            aOff[m][kk] = rowA * 128 + ((g ^ (rowA & 7)) * 16);
            bOff[m][kk] = rowB * 128 + ((g ^ (rowB & 7)) * 16);
        }
    }

    // ---- hoisted staging pointers: lds byte = c*4096 + wave*1024 + lane*16 ----
    const int s_row = wave * 8 + (lane >> 3);
    const int s_col = (((lane & 7) ^ (s_row & 7)) * 8);
    const unsigned short* pA[4];
    const unsigned short* pB[4];
#pragma unroll
    for (int c = 0; c < 4; c++) {
        pA[c] = Xb + (size_t)(rowTile * BM + c * 32 + s_row) * D + s_col;
        pB[c] = Tb + (size_t)(colTile * BN + c * 32 + s_row) * D + s_col;
    }
    char* Asm = smem;
    char* Bsm = smem + 16384;

#pragma unroll
    for (int kt = 0; kt < KT; ++kt) {
        const int k0 = kt * BK;
        __syncthreads();
#pragma unroll
        for (int c = 0; c < 4; ++c) {
            gload16(pA[c] + k0, Asm + c * 4096 + wave * 1024);
            gload16(pB[c] + k0, Bsm + c * 4096 + wave * 1024);
        }
        __syncthreads();
#pragma unroll
        for (int kk = 0; kk < 2; ++kk) {
            short8 a[4], b[4];
#pragma unroll
            for (int m = 0; m < 4; m++) a[m] = *(const short8*)(Asm + aOff[m][kk]);
#pragma unroll
            for (int n = 0; n < 4; n++) b[n] = *(const short8*)(Bsm + bOff[n][kk]);
#pragma unroll
            for (int m = 0; m < 4; m++)
#pragma unroll
                for (int n = 0; n < 4; n++)
                    acc[m][n] = __builtin_amdgcn_mfma_f32_16x16x32_bf16(a[m], b[n], acc[m][n], 0, 0, 0);
        }
    }
    __syncthreads();   // all MFMA-feeding ds_reads done before key overwrite

    // keys: key = tsq[col] - 2*cross; store u16 at col ^ ((row&12)<<2)
    unsigned short* keys = (unsigned short*)smem;   // [128][128] swizzled
    const int crow = wr * 64 + ((lane >> 4) << 2);
    const int ccol = wc * 64 + (lane & 15);
#pragma unroll
    for (int m = 0; m < 4; m++)
#pragma unroll
        for (int n = 0; n < 4; n++)
#pragma unroll
            for (int r = 0; r < 4; r++) {
                const int row = crow + m * 16 + r;
                const int col = ccol + n * 16;
                float key = fmaf(-2.f, acc[m][n][r], tsqv[n]);
                keys[row * 128 + (col ^ ((row & 12) << 2))] =
                    (unsigned short)(pack32(key) >> 16);
            }
    __syncthreads();

    // branchless per-half top-4: 2 threads/row, each scans 32 u32 words (64 cols)
    const int srow = tid >> 1, h = tid & 1;
    const unsigned sx = (unsigned)((srow & 12) << 2);
    const unsigned* keys32 = (const unsigned*)smem;
    const unsigned base = (unsigned)(srow * 64 + h * 32);
    const unsigned gcb = (unsigned)(colTile * BN + h * 64);
    unsigned m1 = ~0u, m2 = ~0u, m3 = ~0u, m4 = ~0u;
#pragma unroll 8
    for (int ii = 0; ii < 32; ++ii) {
        const unsigned w = (unsigned)((ii + srow) & 31);
        const unsigned pair = keys32[base + w];
        const unsigned gc = gcb + ((w * 2) ^ sx);
        const unsigned v0 = (pair << 16) | gc;
        const unsigned v1 = (pair & 0xFFFF0000u) | (gc + 1);
        unsigned t0, t1, t2;
        t0 = max(m1, v0); m1 = min(m1, v0);
        t1 = max(m2, t0); m2 = min(m2, t0);
        t2 = max(m3, t1); m3 = min(m3, t1);
        m4 = min(m4, t2);
        t0 = max(m1, v1); m1 = min(m1, v1);
        t1 = max(m2, t0); m2 = min(m2, t0);
        t2 = max(m3, t1); m3 = min(m3, t1);
        m4 = min(m4, t2);
    }
    uint4 outv = {m1, m2, m3, m4};
    *reinterpret_cast<uint4*>(
        cand + ((size_t)(rowTile * BM + srow) * NCT + colTile) * TSEL + h * 4) = outv;
}

// ---------------- Kernel 3: approx top-16 -> exact fp32 re-rank -> mean ----------------
__global__ void __launch_bounds__(256) knn_reduce_kernel(
    const float* __restrict__ X, const float* __restrict__ Xt,
    const float* __restrict__ tsq, const float* __restrict__ y,
    const unsigned* __restrict__ cand, float* __restrict__ out) {
    __shared__ unsigned cl[4096];
    __shared__ float xrow[D];
    __shared__ float red[4];
    __shared__ unsigned wmin[4];
    __shared__ float xsqs;
    __shared__ unsigned sel[16];
    __shared__ float exd[16];
    __shared__ unsigned exi[16];
    const int q = blockIdx.x;
    const int tid = threadIdx.x;
    const int lane = tid & 63, wave = tid >> 6;

    const unsigned* cq = cand + (size_t)q * (NCT * TSEL);
#pragma unroll
    for (int j = 0; j < 16; j++) cl[j * 256 + tid] = cq[j * 256 + tid];
    if (tid < D / 4)
        ((float4*)xrow)[tid] = ((const float4*)(X + (size_t)q * D))[tid];
    __syncthreads();

    float xs = 0.f;
#pragma unroll
    for (int j = 0; j < 3; j++) { float v = xrow[tid + j * 256]; xs = fmaf(v, v, xs); }
#pragma unroll
    for (int off = 32; off; off >>= 1) xs += __shfl_down(xs, off);
    if (lane == 0) red[wave] = xs;
    __syncthreads();
    if (tid == 0) xsqs = red[0] + red[1] + red[2] + red[3];

    for (int r = 0; r < 16; r++) {
        unsigned mn = 0xFFFFFFFFu;
#pragma unroll
        for (int j = 0; j < 16; j++) { unsigned v = cl[tid + 256 * j]; mn = v < mn ? v : mn; }
#pragma unroll
        for (int off = 32; off; off >>= 1) {
            unsigned o = (unsigned)__shfl_xor((int)mn, off);
            mn = o < mn ? o : mn;
        }
        if (lane == 0) wmin[wave] = mn;
        __syncthreads();
        unsigned m01 = wmin[0] < wmin[1] ? wmin[0] : wmin[1];
        unsigned m23 = wmin[2] < wmin[3] ? wmin[2] : wmin[3];
        unsigned m = m01 < m23 ? m01 : m23;
        if (tid == 0) sel[r] = m;
#pragma unroll
        for (int j = 0; j < 16; j++)
            if (cl[tid + 256 * j] == m) cl[tid + 256 * j] = 0xFFFFFFFFu;
        __syncthreads();
    }

    for (int cc = wave; cc < 16; cc += 4) {
        const unsigned id = sel[cc] & 0xFFFFu;
        const float* trow = Xt + (size_t)id * D;
        float s = 0.f;
#pragma unroll
        for (int j = 0; j < 12; j++) s = fmaf(xrow[lane + j * 64], trow[lane + j * 64], s);
#pragma unroll
        for (int off = 32; off; off >>= 1) s += __shfl_xor(s, off);
        if (lane == 0) {
            float d2 = xsqs + tsq[id] - 2.f * s;
            exd[cc] = sqrtf(fmaxf(d2, 0.f));
            exi[cc] = id;
        }
    }
    __syncthreads();

    if (tid == 0) {
        bool taken[16];
#pragma unroll
        for (int j = 0; j < 16; j++) taken[j] = false;
        float accy = 0.f;
        for (int k = 0; k < KNN; k++) {
            int best = -1;
            for (int j = 0; j < 16; j++) {
                if (taken[j]) continue;
                if (best < 0 || exd[j] < exd[best] ||
                    (exd[j] == exd[best] && exi[j] < exi[best])) best = j;
            }
            taken[best] = true;
            accy += y[exi[best]];
        }
        out[q] = accy / 7.0f;
    }
}

extern "C" void kernel_launch(void* const* d_in, const int* in_sizes, int n_in,
                              void* d_out, int out_size, void* d_ws, size_t ws_size,
                              hipStream_t stream) {
    const float* X  = (const float*)d_in[0];
    const float* Xt = (const float*)d_in[1];
    const float* y  = (const float*)d_in[2];
    float* out = (float*)d_out;
    char* ws = (char*)d_ws;
    unsigned short* Xb = (unsigned short*)(ws + XB_OFF);
    unsigned short* Tb = (unsigned short*)(ws + TB_OFF);
    float* tsq = (float*)(ws + TSQ_OFF);
    unsigned* cand = (unsigned*)(ws + CAND_OFF);

    prep_kernel<<<dim3(Q + NTRAIN), dim3(192), 0, stream>>>(X, Xt, Xb, Tb, tsq);
    knn_gemm_kernel<<<dim3(Q / BM, NCT), dim3(256), 0, stream>>>(Xb, Tb, tsq, cand);
    knn_reduce_kernel<<<dim3(Q), dim3(256), 0, stream>>>(X, Xt, tsq, y, cand, out);
}